// Round 1
// baseline (2376.475 us; speedup 1.0000x reference)
//
#include <hip/hip_runtime.h>
#include <stdint.h>

// ---------------------------------------------------------------------------
// Model constants
#define LSEQ 768
#define DM   256
#define NH   8
#define DK   32
#define DFF  1024
#define NLAYER 8
#define NDD  1535            // distinct (i-j)+767 values
// ---------------------------------------------------------------------------

typedef __attribute__((ext_vector_type(8))) short  bf16x8;
typedef __attribute__((ext_vector_type(4))) float  f32x4;

__device__ __forceinline__ unsigned short f2bf(float f) {
  unsigned u = __float_as_uint(f);
  u += 0x7fffu + ((u >> 16) & 1u);       // RNE
  return (unsigned short)(u >> 16);
}

// ---------------------------------------------------------------------------
// bucket LUT + attention bias table:
//  lut[dd]  = bucket(rel = dd-767)
//  abias[dd*8+h] = rp_emb[lut[dd]][h]
// Mirrors reference f32 op order exactly.
__global__ void k_tables(const float* __restrict__ rp_emb,
                         int* __restrict__ lut, float* __restrict__ abias) {
  int dd = blockIdx.x * 256 + threadIdx.x;
  if (dd >= NDD) return;
  int rel = dd - 767;
  int ret = rel < 0 ? 32 : 0;
  int arp = rel < 0 ? -rel : rel;
  int b;
  if (arp < 16) {
    b = ret + arp;
  } else {
    const float lr = 2.772588722239781f;     // float(np.log(16))
    float val = logf((float)arp * 0.0625f) / lr * 16.0f;
    int vi = 16 + (int)val;
    b = ret + (vi < 31 ? vi : 31);
  }
  lut[dd] = b;
  #pragma unroll
  for (int h = 0; h < NH; ++h) abias[dd * 8 + h] = rp_emb[b * 8 + h];
}

// ---------------------------------------------------------------------------
__global__ void k_embed(const int* __restrict__ seq,
                        const float* __restrict__ tok_emb, float* __restrict__ x) {
  int i = blockIdx.x, c = threadIdx.x * 4;
  *(float4*)(x + i * DM + c) = *(const float4*)(tok_emb + seq[i] * DM + c);
}

// ---------------------------------------------------------------------------
// W1s chunk-packed bf16: W1s[kc*8192 + n*32 + cp] = bf16(cls_w1[(kc*32+cp)*256 + n])
// -> staging a K-chunk into LDS is a flat contiguous 16KB copy.
__global__ void k_prep_w1(const float* __restrict__ w1, unsigned short* __restrict__ W1s) {
  int idx = (blockIdx.x * 256 + threadIdx.x) * 4;
  #pragma unroll
  for (int u = 0; u < 4; ++u) {
    int id = idx + u;
    int kc = id >> 13, rem = id & 8191, n = rem >> 5, cp = rem & 31;
    W1s[id] = f2bf(w1[(kc * 32 + cp) * 256 + n]);
  }
}

// ---------------------------------------------------------------------------
// Generic fp32 GEMM, 64x64 tile, BK=16, 256 threads, 4x4 microtile.
// Optional: fused LayerNorm of A rows (LN), GELU epilogue, residual add,
// row-gather on A (for the RB table build). Up to 3 (B,bias,C) sets selected
// by the n-block (qkv / pair q,k fused launches).
struct GArgs {
  const float* A;
  const float* gatherSrc; const int* gather;
  const float* B[3]; const float* bias[3]; float* C[3];
  const float* res; const float* lns; const float* lnb;
  int M, K, Nper;
};

template <int LN, int GELU, int RES>
__global__ __launch_bounds__(256) void gemm_k(GArgs g) {
  __shared__ float As[16][68];
  __shared__ float Bs[16][68];
  __shared__ float stat[64][2];
  __shared__ float red[64][8];

  int t = threadIdx.x;
  int m0 = blockIdx.y * 64;
  int n0g = blockIdx.x * 64;
  int bi = n0g / g.Nper;
  int n0 = n0g - bi * g.Nper;
  const float* Bp  = g.B[bi];
  const float* bias = g.bias[bi];
  float* Cp = g.C[bi];

  int lr = t >> 2, lq = t & 3;            // A-tile load: row, k-quarter
  int mg = m0 + lr;
  int mgc = mg < g.M ? mg : g.M - 1;
  const float* Ar = g.gather ? (g.gatherSrc + (size_t)g.gather[mgc] * g.K)
                             : (g.A + (size_t)mgc * g.K);
  if (LN) {                               // row stats from raw A
    float s = 0.f, s2 = 0.f;
    const float* p = Ar + lq * 64;
    #pragma unroll
    for (int c = 0; c < 64; c += 4) {
      float4 v = *(const float4*)(p + c);
      s  += v.x + v.y + v.z + v.w;
      s2 += v.x * v.x + v.y * v.y + v.z * v.z + v.w * v.w;
    }
    red[lr][lq] = s; red[lr][lq + 4] = s2;
    __syncthreads();
    if (lq == 0) {
      float sm = red[lr][0] + red[lr][1] + red[lr][2] + red[lr][3];
      float sq = red[lr][4] + red[lr][5] + red[lr][6] + red[lr][7];
      float mean = sm * (1.f / 256.f);
      float var  = sq * (1.f / 256.f) - mean * mean;
      stat[lr][0] = mean;
      stat[lr][1] = rsqrtf(var + 1e-5f);
    }
    __syncthreads();
  }

  float acc[4][4] = {};
  int ty = t >> 4, tx = t & 15;
  int brow = t >> 4, bcol = (t & 15) * 4;
  int ak = lq * 4;

  int kIter = g.K >> 4;
  for (int kt = 0; kt < kIter; ++kt) {
    int k0 = kt << 4;
    float4 av = *(const float4*)(Ar + k0 + ak);
    if (LN) {
      float mean = stat[lr][0], rstd = stat[lr][1];
      float4 ls = *(const float4*)(g.lns + k0 + ak);
      float4 lb = *(const float4*)(g.lnb + k0 + ak);
      av.x = (av.x - mean) * rstd * ls.x + lb.x;
      av.y = (av.y - mean) * rstd * ls.y + lb.y;
      av.z = (av.z - mean) * rstd * ls.z + lb.z;
      av.w = (av.w - mean) * rstd * ls.w + lb.w;
    }
    As[ak + 0][lr] = av.x; As[ak + 1][lr] = av.y;
    As[ak + 2][lr] = av.z; As[ak + 3][lr] = av.w;
    *(float4*)&Bs[brow][bcol] =
        *(const float4*)(Bp + (size_t)(k0 + brow) * g.Nper + n0 + bcol);
    __syncthreads();
    #pragma unroll
    for (int kk = 0; kk < 16; ++kk) {
      float4 a = *(float4*)&As[kk][ty * 4];
      float4 b = *(float4*)&Bs[kk][tx * 4];
      acc[0][0] = fmaf(a.x, b.x, acc[0][0]); acc[0][1] = fmaf(a.x, b.y, acc[0][1]);
      acc[0][2] = fmaf(a.x, b.z, acc[0][2]); acc[0][3] = fmaf(a.x, b.w, acc[0][3]);
      acc[1][0] = fmaf(a.y, b.x, acc[1][0]); acc[1][1] = fmaf(a.y, b.y, acc[1][1]);
      acc[1][2] = fmaf(a.y, b.z, acc[1][2]); acc[1][3] = fmaf(a.y, b.w, acc[1][3]);
      acc[2][0] = fmaf(a.z, b.x, acc[2][0]); acc[2][1] = fmaf(a.z, b.y, acc[2][1]);
      acc[2][2] = fmaf(a.z, b.z, acc[2][2]); acc[2][3] = fmaf(a.z, b.w, acc[2][3]);
      acc[3][0] = fmaf(a.w, b.x, acc[3][0]); acc[3][1] = fmaf(a.w, b.y, acc[3][1]);
      acc[3][2] = fmaf(a.w, b.z, acc[3][2]); acc[3][3] = fmaf(a.w, b.w, acc[3][3]);
    }
    __syncthreads();
  }

  #pragma unroll
  for (int u = 0; u < 4; ++u) {
    int m = m0 + ty * 4 + u;
    if (m < g.M) {
      #pragma unroll
      for (int vv = 0; vv < 4; ++vv) {
        int n = n0 + tx * 4 + vv;
        float val = acc[u][vv];
        if (bias) val += bias[n];
        if (GELU) val = 0.5f * val * (1.f + erff(val * 0.70710678118654752f));
        if (RES) val += g.res[(size_t)m * g.Nper + n];
        Cp[(size_t)m * g.Nper + n] = val;
      }
    }
  }
}

// ---------------------------------------------------------------------------
// Attention: one block per (16 query rows, head). Scores+softmax in LDS.
__global__ __launch_bounds__(256) void k_attn(
    const float* __restrict__ q, const float* __restrict__ k,
    const float* __restrict__ v, const float* __restrict__ abias,
    float* __restrict__ o) {
  __shared__ float S[16][776];            // 776 stride: conflict-free O-phase
  __shared__ float qs[16][32];
  __shared__ float red[16][16];
  __shared__ float mrow[16], linv[16];

  int i0 = blockIdx.x * 16;
  int h = blockIdx.y, hc = h * DK;
  int t = threadIdx.x;

  if (t < 128) {
    int ti = t >> 3, c4 = (t & 7) * 4;
    float4 qv = *(const float4*)(q + (size_t)(i0 + ti) * DM + hc + c4);
    const float inv = 0.17677669529663687f;   // 1/sqrt(32)
    qs[ti][c4 + 0] = qv.x * inv; qs[ti][c4 + 1] = qv.y * inv;
    qs[ti][c4 + 2] = qv.z * inv; qs[ti][c4 + 3] = qv.w * inv;
  }
  __syncthreads();

  int ti = t >> 4, tj = t & 15;
  float mx = -1e30f;
  for (int jc = 0; jc < 48; ++jc) {
    int j = jc * 16 + tj;
    const float* kr = k + (size_t)j * DM + hc;
    float acc = 0.f;
    #pragma unroll
    for (int c = 0; c < 32; c += 4) {
      float4 kv = *(const float4*)(kr + c);
      acc = fmaf(qs[ti][c + 0], kv.x, acc);
      acc = fmaf(qs[ti][c + 1], kv.y, acc);
      acc = fmaf(qs[ti][c + 2], kv.z, acc);
      acc = fmaf(qs[ti][c + 3], kv.w, acc);
    }
    acc += abias[(size_t)(i0 + ti - j + 767) * 8 + h];
    S[ti][j] = acc;
    mx = fmaxf(mx, acc);
  }
  red[ti][tj] = mx;
  __syncthreads();
  if (tj == 0) {
    float m2 = red[ti][0];
    #pragma unroll
    for (int u = 1; u < 16; ++u) m2 = fmaxf(m2, red[ti][u]);
    mrow[ti] = m2;
  }
  __syncthreads();
  float m2 = mrow[ti];
  float sum = 0.f;
  for (int jc = 0; jc < 48; ++jc) {
    int j = jc * 16 + tj;
    float e = __expf(S[ti][j] - m2);
    S[ti][j] = e;
    sum += e;
  }
  red[ti][tj] = sum;
  __syncthreads();
  if (tj == 0) {
    float s2 = 0.f;
    #pragma unroll
    for (int u = 0; u < 16; ++u) s2 += red[ti][u];
    linv[ti] = 1.f / s2;
  }
  __syncthreads();

  int io = t >> 5, c = t & 31;
  for (int half = 0; half < 2; ++half) {
    int i = half * 8 + io;
    float a0 = 0.f, a1 = 0.f, a2 = 0.f, a3 = 0.f;
    const float* vp = v + hc + c;
    for (int j = 0; j < LSEQ; j += 4) {
      a0 = fmaf(S[i][j + 0], vp[(size_t)(j + 0) * DM], a0);
      a1 = fmaf(S[i][j + 1], vp[(size_t)(j + 1) * DM], a1);
      a2 = fmaf(S[i][j + 2], vp[(size_t)(j + 2) * DM], a2);
      a3 = fmaf(S[i][j + 3], vp[(size_t)(j + 3) * DM], a3);
    }
    o[(size_t)(i0 + i) * DM + hc + c] = (a0 + a1 + a2 + a3) * linv[i];
  }
}

// ---------------------------------------------------------------------------
// Fused pair head (the 77 GFLOP op), bf16 MFMA 16x16x32.
// Block tile: 4 i x 32 j = 128 rows, full N=256, K=256 (8 chunks of 32).
// A[r][c] = bf16(q[i][c]*k[j][c]) generated once into LDS.
// B = W1 chunk-packed bf16 (double-buffered LDS).
// Epilogue: T += RB[i-j] (fp32 LDS), relu, dot with W2 cols, shuffle-reduce,
// atomicAdd into per-row LDS acc, coalesced 2-float/row store.
// LDS layout (bytes):
//   A_s  [128][264] bf16  @ 0       (67,584)
//   B_s  [2][8192]  bf16  @ 67584   (32,768)
//   RB_s [35][260]  f32   @ 100352  (36,400)
//   racc [256]      f32   @ 136752  ( 1,024)   total 137,776
#define PAIR_SMEM 137776

__global__ __launch_bounds__(256, 1) void k_pair(
    const float* __restrict__ pq, const float* __restrict__ pk,
    const unsigned short* __restrict__ W1s, const float* __restrict__ RB,
    const float* __restrict__ w2, const float* __restrict__ b2,
    float* __restrict__ out) {
  extern __shared__ char smem[];
  unsigned short* A_s = (unsigned short*)smem;             // [128][264]
  unsigned short* B_s = (unsigned short*)(smem + 67584);   // [2][8192]
  float* RB_s = (float*)(smem + 100352);                   // [35][260]
  float* racc = (float*)(smem + 136752);                   // [256]

  int t = threadIdx.x;
  int j0 = blockIdx.x * 32;
  int i0 = blockIdx.y * 4;
  int w = t >> 6, l = t & 63;

  racc[t] = 0.f;

  // ---- A generation (rows r = ii*32 + jl, cols c full 256) ----
  {
    int c = l * 4;
    float4 qv[4];
    #pragma unroll
    for (int ii = 0; ii < 4; ++ii)
      qv[ii] = *(const float4*)(pq + (size_t)(i0 + ii) * DM + c);
    #pragma unroll
    for (int jj = 0; jj < 8; ++jj) {
      int jl = w * 8 + jj;
      float4 kv = *(const float4*)(pk + (size_t)(j0 + jl) * DM + c);
      #pragma unroll
      for (int ii = 0; ii < 4; ++ii) {
        int r = ii * 32 + jl;
        uint2 pkd;
        pkd.x = (unsigned)f2bf(qv[ii].x * kv.x) | ((unsigned)f2bf(qv[ii].y * kv.y) << 16);
        pkd.y = (unsigned)f2bf(qv[ii].z * kv.z) | ((unsigned)f2bf(qv[ii].w * kv.w) << 16);
        *(uint2*)(A_s + r * 264 + c) = pkd;
      }
    }
  }
  // ---- RB slice stage (35 consecutive dd rows, fp32) ----
  {
    int ddmin = i0 - j0 + 736;          // (i0 - (j0+31)) + 767, always in [0,1500]
    for (int idx = t; idx < 35 * 64; idx += 256) {
      int lc = idx >> 6, c4 = (idx & 63) * 4;
      *(float4*)(RB_s + lc * 260 + c4) =
          *(const float4*)(RB + (size_t)(ddmin + lc) * 256 + c4);
    }
  }
  // ---- B chunk 0 -> buf 0 (flat 16 KB copy) ----
  {
    const uint4* src = (const uint4*)W1s;
    uint4* dst = (uint4*)B_s;
    #pragma unroll
    for (int u = 0; u < 4; ++u) dst[t * 4 + u] = src[t * 4 + u];
  }
  __syncthreads();

  int mwv = w & 1, nwv = w >> 1;        // wave grid 2x2: 64 rows x 128 n each
  int q4 = l >> 4, l15 = l & 15;
  f32x4 acc[4][8];
  #pragma unroll
  for (int a = 0; a < 4; ++a)
    #pragma unroll
    for (int b = 0; b < 8; ++b) acc[a][b] = (f32x4){0.f, 0.f, 0.f, 0.f};

  for (int kc = 0; kc < 8; ++kc) {
    uint4 pre[4];
    if (kc < 7) {                       // prefetch next chunk into regs
      const uint4* src = (const uint4*)W1s + (size_t)(kc + 1) * 1024;
      #pragma unroll
      for (int u = 0; u < 4; ++u) pre[u] = src[t * 4 + u];
    }
    bf16x8 af[4], bfv[8];
    #pragma unroll
    for (int mt = 0; mt < 4; ++mt)
      af[mt] = *(const bf16x8*)(A_s + (mwv * 64 + mt * 16 + l15) * 264 + kc * 32 + q4 * 8);
    #pragma unroll
    for (int nt = 0; nt < 8; ++nt)
      bfv[nt] = *(const bf16x8*)(B_s + (kc & 1) * 8192 + (nwv * 128 + nt * 16 + l15) * 32 + q4 * 8);
    #pragma unroll
    for (int mt = 0; mt < 4; ++mt)
      #pragma unroll
      for (int nt = 0; nt < 8; ++nt)
        acc[mt][nt] = __builtin_amdgcn_mfma_f32_16x16x32_bf16(af[mt], bfv[nt], acc[mt][nt], 0, 0, 0);
    if (kc < 7) {                       // write prefetched chunk to other buf
      uint4* dst = (uint4*)B_s + ((kc + 1) & 1) * 1024;
      #pragma unroll
      for (int u = 0; u < 4; ++u) dst[t * 4 + u] = pre[u];
    }
    __syncthreads();
  }

  // ---- epilogue: +RB, relu, xW2, reduce ----
  float w20[8], w21[8];
  #pragma unroll
  for (int nt = 0; nt < 8; ++nt) {
    int n = nwv * 128 + nt * 16 + l15;
    w20[nt] = w2[n * 2];
    w21[nt] = w2[n * 2 + 1];
  }
  #pragma unroll
  for (int mt = 0; mt < 4; ++mt) {
    #pragma unroll
    for (int reg = 0; reg < 4; ++reg) {
      int r = mwv * 64 + mt * 16 + q4 * 4 + reg;     // D row = quad*4+reg
      int lc = (r >> 5) - (r & 31) + 31;             // local dd
      float o0 = 0.f, o1 = 0.f;
      #pragma unroll
      for (int nt = 0; nt < 8; ++nt) {
        int n = nwv * 128 + nt * 16 + l15;           // D col = lane&15
        float T = acc[mt][nt][reg] + RB_s[lc * 260 + n];
        T = fmaxf(T, 0.f);
        o0 = fmaf(T, w20[nt], o0);
        o1 = fmaf(T, w21[nt], o1);
      }
      #pragma unroll
      for (int s = 1; s < 16; s <<= 1) {
        o0 += __shfl_xor(o0, s);
        o1 += __shfl_xor(o1, s);
      }
      if (l15 == 0) {
        atomicAdd(&racc[r * 2 + 0], o0);
        atomicAdd(&racc[r * 2 + 1], o1);
      }
    }
  }
  __syncthreads();
  {
    int r = t >> 1, oo = t & 1;
    int i = i0 + (r >> 5), j = j0 + (r & 31);
    out[((size_t)i * LSEQ + j) * 2 + oo] = racc[t] + b2[oo];
  }
}

// ---------------------------------------------------------------------------
extern "C" void kernel_launch(void* const* d_in, const int* in_sizes, int n_in,
                              void* d_out, int out_size, void* d_ws, size_t ws_size,
                              hipStream_t stream) {
  const int*   seq      = (const int*)  d_in[0];
  const float* tok_emb  = (const float*)d_in[1];
  const float* rp_emb   = (const float*)d_in[2];
  const float* wq       = (const float*)d_in[3];
  const float* wk       = (const float*)d_in[4];
  const float* wv       = (const float*)d_in[5];
  const float* wo       = (const float*)d_in[6];
  const float* ln1_s    = (const float*)d_in[7];
  const float* ln1_b    = (const float*)d_in[8];
  const float* ln2_s    = (const float*)d_in[9];
  const float* ln2_b    = (const float*)d_in[10];
  const float* ffn_w1   = (const float*)d_in[11];
  const float* ffn_b1   = (const float*)d_in[12];
  const float* ffn_w2   = (const float*)d_in[13];
  const float* ffn_b2   = (const float*)d_in[14];
  const float* lnf_s    = (const float*)d_in[15];
  const float* lnf_b    = (const float*)d_in[16];
  const float* pair_q_w = (const float*)d_in[17];
  const float* pair_q_b = (const float*)d_in[18];
  const float* pair_k_w = (const float*)d_in[19];
  const float* pair_k_b = (const float*)d_in[20];
  const float* pair_rp  = (const float*)d_in[21];
  const float* cls_w1   = (const float*)d_in[22];
  const float* cls_b1   = (const float*)d_in[23];
  const float* cls_w2   = (const float*)d_in[24];
  const float* cls_b2   = (const float*)d_in[25];
  float* out = (float*)d_out;

  // workspace carve (≈10.4 MB)
  char* ws = (char*)d_ws;
  float* x   = (float*)(ws + 0);          // [768][256]
  float* q   = (float*)(ws + 786432);
  float* k   = (float*)(ws + 1572864);
  float* v   = (float*)(ws + 2359296);
  float* o   = (float*)(ws + 3145728);
  float* f1  = (float*)(ws + 3932160);    // [768][1024]
  float* pq  = (float*)(ws + 7077888);
  float* pk  = (float*)(ws + 7864320);
  float* RB  = (float*)(ws + 8650752);    // [1536][256]
  unsigned short* W1s = (unsigned short*)(ws + 10223616);  // [8][256][32] bf16
  int*   lut   = (int*)  (ws + 10354688);
  float* abias = (float*)(ws + 10360832); // [1535][8]

  (void)in_sizes; (void)n_in; (void)out_size; (void)ws_size;

  hipFuncSetAttribute(reinterpret_cast<const void*>(k_pair),
                      hipFuncAttributeMaxDynamicSharedMemorySize, PAIR_SMEM);

  k_tables<<<6, 256, 0, stream>>>(rp_emb, lut, abias);
  k_embed<<<LSEQ, 64, 0, stream>>>(seq, tok_emb, x);
  k_prep_w1<<<64, 256, 0, stream>>>(cls_w1, W1s);

  // RB = pair_rp_emb[lut] @ cls_w1 + cls_b1   [1535][256]
  {
    GArgs a{};
    a.gatherSrc = pair_rp; a.gather = lut;
    a.B[0] = cls_w1; a.bias[0] = cls_b1; a.C[0] = RB;
    a.M = NDD; a.K = DM; a.Nper = DM;
    gemm_k<0, 0, 0><<<dim3(4, 24), 256, 0, stream>>>(a);
  }

  for (int lyr = 0; lyr < NLAYER; ++lyr) {
    const float* wq_l = wq + (size_t)lyr * DM * DM;
    const float* wk_l = wk + (size_t)lyr * DM * DM;
    const float* wv_l = wv + (size_t)lyr * DM * DM;
    const float* wo_l = wo + (size_t)lyr * DM * DM;
    const float* fw1_l = ffn_w1 + (size_t)lyr * DM * DFF;
    const float* fb1_l = ffn_b1 + (size_t)lyr * DFF;
    const float* fw2_l = ffn_w2 + (size_t)lyr * DFF * DM;
    const float* fb2_l = ffn_b2 + (size_t)lyr * DM;

    // q,k,v = LN1(x) @ {Wq,Wk,Wv}
    {
      GArgs a{};
      a.A = x; a.lns = ln1_s + lyr * DM; a.lnb = ln1_b + lyr * DM;
      a.B[0] = wq_l; a.B[1] = wk_l; a.B[2] = wv_l;
      a.C[0] = q; a.C[1] = k; a.C[2] = v;
      a.M = LSEQ; a.K = DM; a.Nper = DM;
      gemm_k<1, 0, 0><<<dim3(12, 12), 256, 0, stream>>>(a);
    }
    k_attn<<<dim3(48, 8), 256, 0, stream>>>(q, k, v, abias, o);
    // x += o @ Wo
    {
      GArgs a{};
      a.A = o; a.B[0] = wo_l; a.C[0] = x; a.res = x;
      a.M = LSEQ; a.K = DM; a.Nper = DM;
      gemm_k<0, 0, 1><<<dim3(4, 12), 256, 0, stream>>>(a);
    }
    // f1 = gelu(LN2(x) @ fw1 + fb1)
    {
      GArgs a{};
      a.A = x; a.lns = ln2_s + lyr * DM; a.lnb = ln2_b + lyr * DM;
      a.B[0] = fw1_l; a.bias[0] = fb1_l; a.C[0] = f1;
      a.M = LSEQ; a.K = DM; a.Nper = DFF;
      gemm_k<1, 1, 0><<<dim3(16, 12), 256, 0, stream>>>(a);
    }
    // x += f1 @ fw2 + fb2
    {
      GArgs a{};
      a.A = f1; a.B[0] = fw2_l; a.bias[0] = fb2_l; a.C[0] = x; a.res = x;
      a.M = LSEQ; a.K = DFF; a.Nper = DM;
      gemm_k<0, 0, 1><<<dim3(4, 12), 256, 0, stream>>>(a);
    }
  }

  // pq, pk = LNf(x) @ {pair_q_w, pair_k_w} + bias
  {
    GArgs a{};
    a.A = x; a.lns = lnf_s; a.lnb = lnf_b;
    a.B[0] = pair_q_w; a.B[1] = pair_k_w;
    a.bias[0] = pair_q_b; a.bias[1] = pair_k_b;
    a.C[0] = pq; a.C[1] = pk;
    a.M = LSEQ; a.K = DM; a.Nper = DM;
    gemm_k<1, 0, 0><<<dim3(8, 12), 256, 0, stream>>>(a);
  }

  // fused pair head
  k_pair<<<dim3(24, 192), 256, PAIR_SMEM, stream>>>(pq, pk, W1s, RB, cls_w2, cls_b2, out);
}

// Round 2
// 2050.836 us; speedup vs baseline: 1.1588x; 1.1588x over previous
//
#include <hip/hip_runtime.h>
#include <stdint.h>

// ---------------------------------------------------------------------------
#define LSEQ 768
#define DM   256
#define NH   8
#define DK   32
#define DFF  1024
#define NLAYER 8
#define NDD  1535
// ---------------------------------------------------------------------------

typedef __attribute__((ext_vector_type(8))) short  bf16x8;
typedef __attribute__((ext_vector_type(4))) float  f32x4;

__device__ __forceinline__ unsigned short f2bf(float f) {
  unsigned u = __float_as_uint(f);
  u += 0x7fffu + ((u >> 16) & 1u);       // RNE
  return (unsigned short)(u >> 16);
}

// ---------------------------------------------------------------------------
// Merged prep: blocks 0..5 = bucket LUT + attn bias; 6..197 = embedding;
// 198..261 = W1 fragment-order bf16 pack.
__global__ __launch_bounds__(256) void k_prep(
    const float* __restrict__ rp_emb, int* __restrict__ lut,
    float* __restrict__ abias,
    const int* __restrict__ seq, const float* __restrict__ tok_emb,
    float* __restrict__ x,
    const float* __restrict__ w1, unsigned short* __restrict__ W1p) {
  int b = blockIdx.x, t = threadIdx.x;
  if (b < 6) {
    int dd = b * 256 + t;
    if (dd >= NDD) return;
    int rel = dd - 767;
    int ret = rel < 0 ? 32 : 0;
    int arp = rel < 0 ? -rel : rel;
    int bk;
    if (arp < 16) {
      bk = ret + arp;
    } else {
      const float lr = 2.772588722239781f;   // float(np.log(16))
      float val = logf((float)arp * 0.0625f) / lr * 16.0f;
      int vi = 16 + (int)val;
      bk = ret + (vi < 31 ? vi : 31);
    }
    lut[dd] = bk;
    #pragma unroll
    for (int h = 0; h < NH; ++h) abias[dd * 8 + h] = rp_emb[bk * 8 + h];
  } else if (b < 198) {
    int row = (b - 6) * 4 + (t >> 6), c = (t & 63) * 4;
    *(float4*)(x + (size_t)row * DM + c) =
        *(const float4*)(tok_emb + (size_t)seq[row] * DM + c);
  } else {
    // W1p[kc*8192 + g*512 + lane*8 + e] = bf16(w1[(kc*32+(lane>>4)*8+e)*256 + g*16+(lane&15)])
    int base = (b - 198) * 1024 + t * 4;
    #pragma unroll
    for (int u = 0; u < 4; ++u) {
      int id = base + u;
      int e = id & 7, lane = (id >> 3) & 63, g = (id >> 9) & 15, kc = id >> 13;
      int kg = kc * 32 + (lane >> 4) * 8 + e;
      int n  = g * 16 + (lane & 15);
      W1p[id] = f2bf(w1[(size_t)kg * 256 + n]);
    }
  }
}

// ---------------------------------------------------------------------------
// fp32 GEMM, 64x64 tile, BK=32, register-prefetch double-buffered LDS.
// Optional fused LN on A rows, GELU, residual, row-gather, 3 (B,bias,C) sets.
struct GArgs {
  const float* A;
  const float* gatherSrc; const int* gather;
  const float* B[3]; const float* bias[3]; float* C[3];
  const float* res; const float* lns; const float* lnb;
  int M, K, Nper;
};

template <int LN, int GELU, int RES>
__global__ __launch_bounds__(256) void gemm_k(GArgs g) {
  __shared__ float As[2][32][68];    // [buf][k][row+pad]
  __shared__ float Bs[2][32][68];    // [buf][k][n+pad]
  __shared__ float stat[64][2];
  __shared__ float red[64][8];

  int t = threadIdx.x;
  int m0 = blockIdx.y * 64;
  int n0g = blockIdx.x * 64;
  int bi = n0g / g.Nper;
  int n0 = n0g - bi * g.Nper;
  const float* Bp   = g.B[bi];
  const float* bias = g.bias[bi];
  float* Cp = g.C[bi];

  int arow = t >> 2, akq = (t & 3) * 8;      // A load: row (0..63), k-octet
  int mg = m0 + arow;
  int mgc = mg < g.M ? mg : g.M - 1;
  const float* Ar = g.gather ? (g.gatherSrc + (size_t)g.gather[mgc] * g.K)
                             : (g.A + (size_t)mgc * g.K);
  float mean = 0.f, rstd = 0.f;
  if (LN) {
    int lq = t & 3;
    float s = 0.f, s2 = 0.f;
    const float* p = Ar + lq * 64;
    #pragma unroll
    for (int c = 0; c < 64; c += 4) {
      float4 v = *(const float4*)(p + c);
      s  += v.x + v.y + v.z + v.w;
      s2 += v.x * v.x + v.y * v.y + v.z * v.z + v.w * v.w;
    }
    red[arow][lq] = s; red[arow][lq + 4] = s2;
    __syncthreads();
    if (lq == 0) {
      float sm = red[arow][0] + red[arow][1] + red[arow][2] + red[arow][3];
      float sq = red[arow][4] + red[arow][5] + red[arow][6] + red[arow][7];
      float m = sm * (1.f / 256.f);
      float v = sq * (1.f / 256.f) - m * m;
      stat[arow][0] = m;
      stat[arow][1] = rsqrtf(v + 1e-5f);
    }
    __syncthreads();
    mean = stat[arow][0]; rstd = stat[arow][1];
  }

  int bkr = t >> 3, bn8 = (t & 7) * 8;       // B load: k-row, n-octet
  int ty = t >> 4, tx = t & 15;
  float acc[4][4] = {};

  int nk = g.K >> 5;
  float4 a0, a1, b0, b1;

  // prologue load chunk 0
  {
    a0 = *(const float4*)(Ar + akq);
    a1 = *(const float4*)(Ar + akq + 4);
    if (LN) {
      float4 ls0 = *(const float4*)(g.lns + akq), ls1 = *(const float4*)(g.lns + akq + 4);
      float4 lb0 = *(const float4*)(g.lnb + akq), lb1 = *(const float4*)(g.lnb + akq + 4);
      a0.x = (a0.x-mean)*rstd*ls0.x+lb0.x; a0.y = (a0.y-mean)*rstd*ls0.y+lb0.y;
      a0.z = (a0.z-mean)*rstd*ls0.z+lb0.z; a0.w = (a0.w-mean)*rstd*ls0.w+lb0.w;
      a1.x = (a1.x-mean)*rstd*ls1.x+lb1.x; a1.y = (a1.y-mean)*rstd*ls1.y+lb1.y;
      a1.z = (a1.z-mean)*rstd*ls1.z+lb1.z; a1.w = (a1.w-mean)*rstd*ls1.w+lb1.w;
    }
    b0 = *(const float4*)(Bp + (size_t)bkr * g.Nper + n0 + bn8);
    b1 = *(const float4*)(Bp + (size_t)bkr * g.Nper + n0 + bn8 + 4);
    As[0][akq+0][arow]=a0.x; As[0][akq+1][arow]=a0.y; As[0][akq+2][arow]=a0.z; As[0][akq+3][arow]=a0.w;
    As[0][akq+4][arow]=a1.x; As[0][akq+5][arow]=a1.y; As[0][akq+6][arow]=a1.z; As[0][akq+7][arow]=a1.w;
    *(float4*)&Bs[0][bkr][bn8] = b0;
    *(float4*)&Bs[0][bkr][bn8+4] = b1;
  }
  __syncthreads();

  for (int kt = 0; kt < nk; ++kt) {
    int cur = kt & 1;
    if (kt + 1 < nk) {
      int k0 = (kt + 1) << 5;
      a0 = *(const float4*)(Ar + k0 + akq);
      a1 = *(const float4*)(Ar + k0 + akq + 4);
      if (LN) {
        float4 ls0 = *(const float4*)(g.lns + k0 + akq), ls1 = *(const float4*)(g.lns + k0 + akq + 4);
        float4 lb0 = *(const float4*)(g.lnb + k0 + akq), lb1 = *(const float4*)(g.lnb + k0 + akq + 4);
        a0.x = (a0.x-mean)*rstd*ls0.x+lb0.x; a0.y = (a0.y-mean)*rstd*ls0.y+lb0.y;
        a0.z = (a0.z-mean)*rstd*ls0.z+lb0.z; a0.w = (a0.w-mean)*rstd*ls0.w+lb0.w;
        a1.x = (a1.x-mean)*rstd*ls1.x+lb1.x; a1.y = (a1.y-mean)*rstd*ls1.y+lb1.y;
        a1.z = (a1.z-mean)*rstd*ls1.z+lb1.z; a1.w = (a1.w-mean)*rstd*ls1.w+lb1.w;
      }
      b0 = *(const float4*)(Bp + (size_t)(k0 + bkr) * g.Nper + n0 + bn8);
      b1 = *(const float4*)(Bp + (size_t)(k0 + bkr) * g.Nper + n0 + bn8 + 4);
    }
    #pragma unroll
    for (int kk = 0; kk < 32; ++kk) {
      float4 a = *(float4*)&As[cur][kk][ty * 4];
      float4 b = *(float4*)&Bs[cur][kk][tx * 4];
      acc[0][0]=fmaf(a.x,b.x,acc[0][0]); acc[0][1]=fmaf(a.x,b.y,acc[0][1]);
      acc[0][2]=fmaf(a.x,b.z,acc[0][2]); acc[0][3]=fmaf(a.x,b.w,acc[0][3]);
      acc[1][0]=fmaf(a.y,b.x,acc[1][0]); acc[1][1]=fmaf(a.y,b.y,acc[1][1]);
      acc[1][2]=fmaf(a.y,b.z,acc[1][2]); acc[1][3]=fmaf(a.y,b.w,acc[1][3]);
      acc[2][0]=fmaf(a.z,b.x,acc[2][0]); acc[2][1]=fmaf(a.z,b.y,acc[2][1]);
      acc[2][2]=fmaf(a.z,b.z,acc[2][2]); acc[2][3]=fmaf(a.z,b.w,acc[2][3]);
      acc[3][0]=fmaf(a.w,b.x,acc[3][0]); acc[3][1]=fmaf(a.w,b.y,acc[3][1]);
      acc[3][2]=fmaf(a.w,b.z,acc[3][2]); acc[3][3]=fmaf(a.w,b.w,acc[3][3]);
    }
    if (kt + 1 < nk) {
      int nxt = cur ^ 1;
      As[nxt][akq+0][arow]=a0.x; As[nxt][akq+1][arow]=a0.y; As[nxt][akq+2][arow]=a0.z; As[nxt][akq+3][arow]=a0.w;
      As[nxt][akq+4][arow]=a1.x; As[nxt][akq+5][arow]=a1.y; As[nxt][akq+6][arow]=a1.z; As[nxt][akq+7][arow]=a1.w;
      *(float4*)&Bs[nxt][bkr][bn8] = b0;
      *(float4*)&Bs[nxt][bkr][bn8+4] = b1;
    }
    __syncthreads();
  }

  #pragma unroll
  for (int u = 0; u < 4; ++u) {
    int m = m0 + ty * 4 + u;
    if (m < g.M) {
      #pragma unroll
      for (int vv = 0; vv < 4; ++vv) {
        int n = n0 + tx * 4 + vv;
        float val = acc[u][vv];
        if (bias) val += bias[n];
        if (GELU) val = 0.5f * val * (1.f + erff(val * 0.70710678118654752f));
        if (RES) val += g.res[(size_t)m * g.Nper + n];
        Cp[(size_t)m * g.Nper + n] = val;
      }
    }
  }
}

// ---------------------------------------------------------------------------
// Attention: one block per (16 query rows, head).
__global__ __launch_bounds__(256) void k_attn(
    const float* __restrict__ q, const float* __restrict__ k,
    const float* __restrict__ v, const float* __restrict__ abias,
    float* __restrict__ o) {
  __shared__ float S[16][776];
  __shared__ float red[16][16];
  __shared__ float mrow[16], linv[16];
  __shared__ float pr[16 * 4 * 36];   // [i][wave][c+pad]

  int i0 = blockIdx.x * 16;
  int h = blockIdx.y, hc = h * DK;
  int t = threadIdx.x;
  int ti = t >> 4, tj = t & 15;

  // q row into registers (scaled)
  float qr[32];
  {
    const float* qp = q + (size_t)(i0 + ti) * DM + hc;
    const float inv = 0.17677669529663687f;   // 1/sqrt(32)
    #pragma unroll
    for (int c = 0; c < 32; c += 4) {
      float4 v4 = *(const float4*)(qp + c);
      qr[c+0] = v4.x * inv; qr[c+1] = v4.y * inv;
      qr[c+2] = v4.z * inv; qr[c+3] = v4.w * inv;
    }
  }

  float mx = -1e30f;
  for (int jc = 0; jc < 48; ++jc) {
    int j = jc * 16 + tj;
    const float* kr = k + (size_t)j * DM + hc;
    float acc = 0.f;
    #pragma unroll
    for (int c = 0; c < 32; c += 4) {
      float4 kv = *(const float4*)(kr + c);
      acc = fmaf(qr[c+0], kv.x, acc);
      acc = fmaf(qr[c+1], kv.y, acc);
      acc = fmaf(qr[c+2], kv.z, acc);
      acc = fmaf(qr[c+3], kv.w, acc);
    }
    acc += abias[(size_t)(i0 + ti - j + 767) * 8 + h];
    S[ti][j] = acc;
    mx = fmaxf(mx, acc);
  }
  red[ti][tj] = mx;
  __syncthreads();
  if (tj == 0) {
    float m2 = red[ti][0];
    #pragma unroll
    for (int u = 1; u < 16; ++u) m2 = fmaxf(m2, red[ti][u]);
    mrow[ti] = m2;
  }
  __syncthreads();
  float m2 = mrow[ti];
  float sum = 0.f;
  for (int jc = 0; jc < 48; ++jc) {
    int j = jc * 16 + tj;
    float e = __expf(S[ti][j] - m2);
    S[ti][j] = e;
    sum += e;
  }
  red[ti][tj] = sum;
  __syncthreads();
  if (tj == 0) {
    float s2 = 0.f;
    #pragma unroll
    for (int u = 0; u < 16; ++u) s2 += red[ti][u];
    linv[ti] = 1.f / s2;
  }
  __syncthreads();

  // V phase: wave w owns j-quarter; lane: 4 V-cols x 2 rows (i, i+8)
  {
    int wv = t >> 6, l = t & 63;
    int c4 = (l & 7) * 4;
    int ib = l >> 3;                    // 0..7
    float a00=0,a01=0,a02=0,a03=0, a10=0,a11=0,a12=0,a13=0;
    const float* vp = v + hc + c4;
    int jbeg = wv * 192;
    for (int j = jbeg; j < jbeg + 192; j += 4) {
      float4 s0 = *(float4*)&S[ib][j];
      float4 s1 = *(float4*)&S[ib + 8][j];
      const float* vj = vp + (size_t)j * DM;
      float4 v0 = *(const float4*)(vj);
      float4 v1 = *(const float4*)(vj + DM);
      float4 v2 = *(const float4*)(vj + 2 * DM);
      float4 v3 = *(const float4*)(vj + 3 * DM);
      a00=fmaf(s0.x,v0.x,a00); a01=fmaf(s0.x,v0.y,a01); a02=fmaf(s0.x,v0.z,a02); a03=fmaf(s0.x,v0.w,a03);
      a10=fmaf(s1.x,v0.x,a10); a11=fmaf(s1.x,v0.y,a11); a12=fmaf(s1.x,v0.z,a12); a13=fmaf(s1.x,v0.w,a13);
      a00=fmaf(s0.y,v1.x,a00); a01=fmaf(s0.y,v1.y,a01); a02=fmaf(s0.y,v1.z,a02); a03=fmaf(s0.y,v1.w,a03);
      a10=fmaf(s1.y,v1.x,a10); a11=fmaf(s1.y,v1.y,a11); a12=fmaf(s1.y,v1.z,a12); a13=fmaf(s1.y,v1.w,a13);
      a00=fmaf(s0.z,v2.x,a00); a01=fmaf(s0.z,v2.y,a01); a02=fmaf(s0.z,v2.z,a02); a03=fmaf(s0.z,v2.w,a03);
      a10=fmaf(s1.z,v2.x,a10); a11=fmaf(s1.z,v2.y,a11); a12=fmaf(s1.z,v2.z,a12); a13=fmaf(s1.z,v2.w,a13);
      a00=fmaf(s0.w,v3.x,a00); a01=fmaf(s0.w,v3.y,a01); a02=fmaf(s0.w,v3.z,a02); a03=fmaf(s0.w,v3.w,a03);
      a10=fmaf(s1.w,v3.x,a10); a11=fmaf(s1.w,v3.y,a11); a12=fmaf(s1.w,v3.z,a12); a13=fmaf(s1.w,v3.w,a13);
    }
    pr[(ib * 4 + wv) * 36 + c4 + 0] = a00;
    pr[(ib * 4 + wv) * 36 + c4 + 1] = a01;
    pr[(ib * 4 + wv) * 36 + c4 + 2] = a02;
    pr[(ib * 4 + wv) * 36 + c4 + 3] = a03;
    pr[((ib + 8) * 4 + wv) * 36 + c4 + 0] = a10;
    pr[((ib + 8) * 4 + wv) * 36 + c4 + 1] = a11;
    pr[((ib + 8) * 4 + wv) * 36 + c4 + 2] = a12;
    pr[((ib + 8) * 4 + wv) * 36 + c4 + 3] = a13;
  }
  __syncthreads();
  #pragma unroll
  for (int u = 0; u < 2; ++u) {
    int idx = t * 2 + u;
    int i = idx >> 5, c = idx & 31;
    float s = pr[(i*4+0)*36 + c] + pr[(i*4+1)*36 + c]
            + pr[(i*4+2)*36 + c] + pr[(i*4+3)*36 + c];
    o[(size_t)(i0 + i) * DM + hc + c] = s * linv[i];
  }
}

// ---------------------------------------------------------------------------
// Fused pair head. Register A-gen, global fragment-order B, no K-loop barriers.
// Block: 128 rows (4 i x 32 j) x 256 n. Waves 2x2 (row-half x n-half).
// LDS: RB_s [35][260] f32 @0 (36400) + part [2][128][33] f32 @36400 (33792)
#define PAIR_SMEM (36400 + 33792)

__global__ __launch_bounds__(256, 2) void k_pair(
    const float* __restrict__ pq, const float* __restrict__ pk,
    const unsigned short* __restrict__ W1p, const float* __restrict__ RB,
    const float* __restrict__ w2, const float* __restrict__ b2,
    float* __restrict__ out) {
  extern __shared__ char smem[];
  float* RB_s = (float*)smem;
  float* part = (float*)(smem + 36400);

  int t = threadIdx.x;
  int j0 = blockIdx.x * 32;
  int i0 = blockIdx.y * 4;
  int w = t >> 6, l = t & 63;
  int q4 = l >> 4, l15 = l & 15;
  int mwv = w & 1, nwv = w >> 1;

  // stage RB slice (35 consecutive dd rows)
  {
    int ddmin = i0 - j0 + 736;
    for (int idx = t; idx < 35 * 64; idx += 256) {
      int lc = idx >> 6, c4 = (idx & 63) * 4;
      *(float4*)(RB_s + lc * 260 + c4) =
          *(const float4*)(RB + (size_t)(ddmin + lc) * 256 + c4);
    }
  }

  const float* q0p = pq + (size_t)(i0 + mwv * 2    ) * DM;
  const float* q1p = pq + (size_t)(i0 + mwv * 2 + 1) * DM;
  const float* k0p = pk + (size_t)(j0 + l15        ) * DM;
  const float* k1p = pk + (size_t)(j0 + 16 + l15   ) * DM;
  const unsigned short* Bp = W1p + (size_t)(nwv * 8) * 512 + (size_t)l * 8;

  f32x4 acc[4][8];
  #pragma unroll
  for (int a = 0; a < 4; ++a)
    #pragma unroll
    for (int b = 0; b < 8; ++b) acc[a][b] = (f32x4){0.f, 0.f, 0.f, 0.f};

  #pragma unroll 2
  for (int kc = 0; kc < 8; ++kc) {
    int c = kc * 32 + q4 * 8;
    float4 qa0 = *(const float4*)(q0p + c), qa1 = *(const float4*)(q0p + c + 4);
    float4 qb0 = *(const float4*)(q1p + c), qb1 = *(const float4*)(q1p + c + 4);
    float4 ka0 = *(const float4*)(k0p + c), ka1 = *(const float4*)(k0p + c + 4);
    float4 kb0 = *(const float4*)(k1p + c), kb1 = *(const float4*)(k1p + c + 4);

    bf16x8 bfv[8];
    const unsigned short* bb = Bp + (size_t)kc * 8192;
    #pragma unroll
    for (int nt = 0; nt < 8; ++nt)
      bfv[nt] = *(const bf16x8*)(bb + nt * 512);

    bf16x8 af[4];
    af[0][0]=(short)f2bf(qa0.x*ka0.x); af[0][1]=(short)f2bf(qa0.y*ka0.y);
    af[0][2]=(short)f2bf(qa0.z*ka0.z); af[0][3]=(short)f2bf(qa0.w*ka0.w);
    af[0][4]=(short)f2bf(qa1.x*ka1.x); af[0][5]=(short)f2bf(qa1.y*ka1.y);
    af[0][6]=(short)f2bf(qa1.z*ka1.z); af[0][7]=(short)f2bf(qa1.w*ka1.w);
    af[1][0]=(short)f2bf(qa0.x*kb0.x); af[1][1]=(short)f2bf(qa0.y*kb0.y);
    af[1][2]=(short)f2bf(qa0.z*kb0.z); af[1][3]=(short)f2bf(qa0.w*kb0.w);
    af[1][4]=(short)f2bf(qa1.x*kb1.x); af[1][5]=(short)f2bf(qa1.y*kb1.y);
    af[1][6]=(short)f2bf(qa1.z*kb1.z); af[1][7]=(short)f2bf(qa1.w*kb1.w);
    af[2][0]=(short)f2bf(qb0.x*ka0.x); af[2][1]=(short)f2bf(qb0.y*ka0.y);
    af[2][2]=(short)f2bf(qb0.z*ka0.z); af[2][3]=(short)f2bf(qb0.w*ka0.w);
    af[2][4]=(short)f2bf(qb1.x*ka1.x); af[2][5]=(short)f2bf(qb1.y*ka1.y);
    af[2][6]=(short)f2bf(qb1.z*ka1.z); af[2][7]=(short)f2bf(qb1.w*ka1.w);
    af[3][0]=(short)f2bf(qb0.x*kb0.x); af[3][1]=(short)f2bf(qb0.y*kb0.y);
    af[3][2]=(short)f2bf(qb0.z*kb0.z); af[3][3]=(short)f2bf(qb0.w*kb0.w);
    af[3][4]=(short)f2bf(qb1.x*kb1.x); af[3][5]=(short)f2bf(qb1.y*kb1.y);
    af[3][6]=(short)f2bf(qb1.z*kb1.z); af[3][7]=(short)f2bf(qb1.w*kb1.w);

    #pragma unroll
    for (int mt = 0; mt < 4; ++mt)
      #pragma unroll
      for (int nt = 0; nt < 8; ++nt)
        acc[mt][nt] = __builtin_amdgcn_mfma_f32_16x16x32_bf16(af[mt], bfv[nt], acc[mt][nt], 0, 0, 0);
  }

  __syncthreads();   // RB_s staged; main loop done

  float w20[8], w21[8];
  #pragma unroll
  for (int nt = 0; nt < 8; ++nt) {
    int n = nwv * 128 + nt * 16 + l15;
    w20[nt] = w2[n * 2];
    w21[nt] = w2[n * 2 + 1];
  }
  #pragma unroll
  for (int mt = 0; mt < 4; ++mt) {
    #pragma unroll
    for (int reg = 0; reg < 4; ++reg) {
      int r = mwv * 64 + mt * 16 + q4 * 4 + reg;     // D row = quad*4+reg
      int lc = (r >> 5) - (r & 31) + 31;             // local dd
      float o0 = 0.f, o1 = 0.f;
      #pragma unroll
      for (int nt = 0; nt < 8; ++nt) {
        int n = nwv * 128 + nt * 16 + l15;           // D col = lane&15
        float T = acc[mt][nt][reg] + RB_s[lc * 260 + n];
        T = fmaxf(T, 0.f);
        o0 = fmaf(T, w20[nt], o0);
        o1 = fmaf(T, w21[nt], o1);
      }
      part[0 * 4224 + r * 33 + nwv * 16 + l15] = o0;
      part[1 * 4224 + r * 33 + nwv * 16 + l15] = o1;
    }
  }
  __syncthreads();
  {
    int r = t >> 1, oo = t & 1;
    float s = 0.f;
    #pragma unroll
    for (int c = 0; c < 32; ++c) s += part[oo * 4224 + r * 33 + c];
    out[((size_t)(i0 + (r >> 5)) * LSEQ + (j0 + (r & 31))) * 2 + oo] = s + b2[oo];
  }
}

// ---------------------------------------------------------------------------
extern "C" void kernel_launch(void* const* d_in, const int* in_sizes, int n_in,
                              void* d_out, int out_size, void* d_ws, size_t ws_size,
                              hipStream_t stream) {
  const int*   seq      = (const int*)  d_in[0];
  const float* tok_emb  = (const float*)d_in[1];
  const float* rp_emb   = (const float*)d_in[2];
  const float* wq       = (const float*)d_in[3];
  const float* wk       = (const float*)d_in[4];
  const float* wv       = (const float*)d_in[5];
  const float* wo       = (const float*)d_in[6];
  const float* ln1_s    = (const float*)d_in[7];
  const float* ln1_b    = (const float*)d_in[8];
  const float* ln2_s    = (const float*)d_in[9];
  const float* ln2_b    = (const float*)d_in[10];
  const float* ffn_w1   = (const float*)d_in[11];
  const float* ffn_b1   = (const float*)d_in[12];
  const float* ffn_w2   = (const float*)d_in[13];
  const float* ffn_b2   = (const float*)d_in[14];
  const float* lnf_s    = (const float*)d_in[15];
  const float* lnf_b    = (const float*)d_in[16];
  const float* pair_q_w = (const float*)d_in[17];
  const float* pair_q_b = (const float*)d_in[18];
  const float* pair_k_w = (const float*)d_in[19];
  const float* pair_k_b = (const float*)d_in[20];
  const float* pair_rp  = (const float*)d_in[21];
  const float* cls_w1   = (const float*)d_in[22];
  const float* cls_b1   = (const float*)d_in[23];
  const float* cls_w2   = (const float*)d_in[24];
  const float* cls_b2   = (const float*)d_in[25];
  float* out = (float*)d_out;

  char* ws = (char*)d_ws;
  float* x   = (float*)(ws + 0);          // [768][256]
  float* q   = (float*)(ws + 786432);
  float* k   = (float*)(ws + 1572864);
  float* v   = (float*)(ws + 2359296);
  float* o   = (float*)(ws + 3145728);
  float* f1  = (float*)(ws + 3932160);    // [768][1024]
  float* pq  = (float*)(ws + 7077888);
  float* pk  = (float*)(ws + 7864320);
  float* RB  = (float*)(ws + 8650752);    // [1536][256]
  unsigned short* W1p = (unsigned short*)(ws + 10223616);  // fragment-order bf16 [65536]
  int*   lut   = (int*)  (ws + 10354688);
  float* abias = (float*)(ws + 10360832); // [1535][8]

  (void)in_sizes; (void)n_in; (void)out_size; (void)ws_size;

  hipFuncSetAttribute(reinterpret_cast<const void*>(k_pair),
                      hipFuncAttributeMaxDynamicSharedMemorySize, PAIR_SMEM);

  k_prep<<<262, 256, 0, stream>>>(rp_emb, lut, abias, seq, tok_emb, x, cls_w1, W1p);

  // RB = pair_rp_emb[lut] @ cls_w1 + cls_b1   [1535][256]
  {
    GArgs a{};
    a.gatherSrc = pair_rp; a.gather = lut;
    a.B[0] = cls_w1; a.bias[0] = cls_b1; a.C[0] = RB;
    a.M = NDD; a.K = DM; a.Nper = DM;
    gemm_k<0, 0, 0><<<dim3(4, 24), 256, 0, stream>>>(a);
  }

  for (int lyr = 0; lyr < NLAYER; ++lyr) {
    const float* wq_l = wq + (size_t)lyr * DM * DM;
    const float* wk_l = wk + (size_t)lyr * DM * DM;
    const float* wv_l = wv + (size_t)lyr * DM * DM;
    const float* wo_l = wo + (size_t)lyr * DM * DM;
    const float* fw1_l = ffn_w1 + (size_t)lyr * DM * DFF;
    const float* fb1_l = ffn_b1 + (size_t)lyr * DFF;
    const float* fw2_l = ffn_w2 + (size_t)lyr * DFF * DM;
    const float* fb2_l = ffn_b2 + (size_t)lyr * DM;

    {
      GArgs a{};
      a.A = x; a.lns = ln1_s + lyr * DM; a.lnb = ln1_b + lyr * DM;
      a.B[0] = wq_l; a.B[1] = wk_l; a.B[2] = wv_l;
      a.C[0] = q; a.C[1] = k; a.C[2] = v;
      a.M = LSEQ; a.K = DM; a.Nper = DM;
      gemm_k<1, 0, 0><<<dim3(12, 12), 256, 0, stream>>>(a);
    }
    k_attn<<<dim3(48, 8), 256, 0, stream>>>(q, k, v, abias, o);
    {
      GArgs a{};
      a.A = o; a.B[0] = wo_l; a.C[0] = x; a.res = x;
      a.M = LSEQ; a.K = DM; a.Nper = DM;
      gemm_k<0, 0, 1><<<dim3(4, 12), 256, 0, stream>>>(a);
    }
    {
      GArgs a{};
      a.A = x; a.lns = ln2_s + lyr * DM; a.lnb = ln2_b + lyr * DM;
      a.B[0] = fw1_l; a.bias[0] = fb1_l; a.C[0] = f1;
      a.M = LSEQ; a.K = DM; a.Nper = DFF;
      gemm_k<1, 1, 0><<<dim3(16, 12), 256, 0, stream>>>(a);
    }
    {
      GArgs a{};
      a.A = f1; a.B[0] = fw2_l; a.bias[0] = fb2_l; a.C[0] = x; a.res = x;
      a.M = LSEQ; a.K = DFF; a.Nper = DM;
      gemm_k<0, 0, 1><<<dim3(4, 12), 256, 0, stream>>>(a);
    }
  }

  {
    GArgs a{};
    a.A = x; a.lns = lnf_s; a.lnb = lnf_b;
    a.B[0] = pair_q_w; a.B[1] = pair_k_w;
    a.bias[0] = pair_q_b; a.bias[1] = pair_k_b;
    a.C[0] = pq; a.C[1] = pk;
    a.M = LSEQ; a.K = DM; a.Nper = DM;
    gemm_k<1, 0, 0><<<dim3(8, 12), 256, 0, stream>>>(a);
  }

  k_pair<<<dim3(24, 192), 256, PAIR_SMEM, stream>>>(pq, pk, W1p, RB, cls_w2, cls_b2, out);
}